// Round 9
// baseline (341.377 us; speedup 1.0000x reference)
//
#include <hip/hip_runtime.h>

// HeteroGAT on MI355X. R9 = R8 + fix: NB_WT 128 -> 104 (13 matrices x 8 tiles).
// R8's extra transpose blocks (mat 13..15) wrote 16K u16 past WTIN into WAT,
// clobbering the folded attn matrices (raced with fold) -> Output 0 garbage.
//   memset: zero bucket counters
//   K1 k_prep: scatter (90us contention floor) hiding [feat cvt + W transpose + attn fold]
//   K2 k_gemm: 13 full bf16-MFMA GEMMs (vectorized C-write via stride-132 LDS)
//              + 4 narrow score GEMMs (scores = feat @ folded attn matrices)
//   K3 k_agg: 1 wave/dst node, 4-edge software pipeline

#define H_ 8
#define D_ 32
#define HD 256
#define NC 10000
#define NS 1024
#define INC 128
#define INS 64
#define ECC 120000
#define ECS 10000
#define ALPHA 0.2f
#define CAP 64

typedef unsigned short u16;
typedef __attribute__((ext_vector_type(8))) short short8;
typedef __attribute__((ext_vector_type(4))) float f32x4;

// ---- ws layout ----
// u16 region (u16 units)
static constexpr size_t WHB_CC = 0;              // 9*NC*HD
static constexpr size_t WHB_CS = 23040000;       // 3*NC*HD
static constexpr size_t WHB_IN = 30720000;       // NS*HD -> end 30982144 u16
// f32 scores (float units)
static constexpr size_t FB0  = 15491072;
static constexpr size_t ASCC = FB0;              // 9*NC*8
static constexpr size_t ADCC = FB0 + 720000;     // 9*NC*8
static constexpr size_t ASCS = FB0 + 1440000;    // 3*NC*8
static constexpr size_t ADCS = FB0 + 1680000;    // 3*NS*8 -> FB0+1704576
static constexpr size_t BAF  = FB0 + 1704576;    // 4*64 folded bias dots -> FB0+1704832
// bf16 feats + transposed weights (u16 units)
static constexpr size_t FBC  = 34437760;         // 3*NC*128
static constexpr size_t FBS  = 38277760;         // NS*64
static constexpr size_t WTCC = 38343296;         // 9*32768
static constexpr size_t WTCS = 38638208;         // 3*32768
static constexpr size_t WTIN = 38736512;         // 256*64
static constexpr size_t WAT  = 38752896;         // 4*8192 folded attn mats [col][k] -> end 38785664
// int counters (byte offset): 93072 ints = 9*NC (cc) then 3*NS (cs)
static constexpr size_t IBYTE = 77768704;
// u16 slots (byte offset): slot for counter c is slt[c*CAP + p]
static constexpr size_t SBYTE = 78140992;        // 93072*64 u16 -> end ~90.1 MB

static constexpr int TOTE  = 9 * ECC + 3 * ECS;  // 1,110,000
static constexpr int NB_SC = 542;                // scatter blocks (2048 edges each)
static constexpr int NB_FT = 3814;               // feat cvt
static constexpr int NB_WT = 104;                // weight transpose: 13 mats x 8 (FIX: was 128)
static constexpr int NB_FO = 4;                  // attn fold tiles
// K2 grid: 12*158 full-C + 16 state + 3*79 score-C + 8 score-S = 2157
static constexpr int NB_GE = 2157;

__device__ __forceinline__ u16 f2b(float f) {
  unsigned u = __float_as_uint(f);
  return (u16)((u + 0x7FFFu + ((u >> 16) & 1u)) >> 16);
}
__device__ __forceinline__ float bl(unsigned u) { return __uint_as_float(u << 16); }
__device__ __forceinline__ float bh(unsigned u) { return __uint_as_float(u & 0xffff0000u); }

// ================= K1: scatter + cvt_feat + cvt_w + fold =================
__global__ __launch_bounds__(256) void k_prep(
    const float* f1, const float* f2, const float* f3, const float* fs,
    const float* Wcc, const float* Wcs, const float* Win, const float* Wnode,
    const float* bcc, const float* bnode, const float* bcs, const float* bin,
    const float* accv, const float* acsv,
    const int* eccs, const int* eccd, const int* ecss, const int* ecsd,
    u16* wsu, float* wsf, int* cnts, u16* slt) {
  __shared__ float Ls[64 * 65];
  int b = blockIdx.x, t = threadIdx.x;
  if (b < NB_SC) {                                 // ---- edge scatter, 8/thread ----
    int i0 = (b * 256 + t) * 8;
    if (i0 >= TOTE) return;
    int dd[8], ss[8], p[8];
    int cbase;
    if (i0 < 9 * ECC) {
      int r = i0 / ECC;
      int4 d0 = *(const int4*)&eccd[i0]; int4 d1 = *(const int4*)&eccd[i0 + 4];
      int4 s0 = *(const int4*)&eccs[i0]; int4 s1 = *(const int4*)&eccs[i0 + 4];
      dd[0]=d0.x; dd[1]=d0.y; dd[2]=d0.z; dd[3]=d0.w;
      dd[4]=d1.x; dd[5]=d1.y; dd[6]=d1.z; dd[7]=d1.w;
      ss[0]=s0.x; ss[1]=s0.y; ss[2]=s0.z; ss[3]=s0.w;
      ss[4]=s1.x; ss[5]=s1.y; ss[6]=s1.z; ss[7]=s1.w;
      cbase = r * NC;
    } else {
      int u0 = i0 - 9 * ECC;
      int r = u0 / ECS;
      int4 d0 = *(const int4*)&ecsd[u0]; int4 d1 = *(const int4*)&ecsd[u0 + 4];
      int4 s0 = *(const int4*)&ecss[u0]; int4 s1 = *(const int4*)&ecss[u0 + 4];
      dd[0]=d0.x; dd[1]=d0.y; dd[2]=d0.z; dd[3]=d0.w;
      dd[4]=d1.x; dd[5]=d1.y; dd[6]=d1.z; dd[7]=d1.w;
      ss[0]=s0.x; ss[1]=s0.y; ss[2]=s0.z; ss[3]=s0.w;
      ss[4]=s1.x; ss[5]=s1.y; ss[6]=s1.z; ss[7]=s1.w;
      cbase = 90000 + r * NS;
    }
    #pragma unroll
    for (int q = 0; q < 8; q++) p[q] = atomicAdd(&cnts[cbase + dd[q]], 1);
    #pragma unroll
    for (int q = 0; q < 8; q++)
      if (p[q] < CAP) slt[((size_t)(cbase + dd[q])) * CAP + p[q]] = (u16)ss[q];
    return;
  }
  b -= NB_SC;
  if (b < NB_FT) {                                 // ---- f32 -> bf16 feats ----
    const float* src; u16* dst; int idx, n4;
    if (b < 3750) {
      int ty = b / 1250;
      src = (ty == 0) ? f1 : (ty == 1) ? f2 : f3;
      dst = wsu + FBC + (size_t)ty * 1280000;
      idx = (b - ty * 1250) * 256 + t; n4 = 320000;
    } else {
      src = fs; dst = wsu + FBS; idx = (b - 3750) * 256 + t; n4 = 16384;
    }
    if (idx < n4) {
      float4 v = ((const float4*)src)[idx];
      uint2 o;
      o.x = (unsigned)f2b(v.x) | ((unsigned)f2b(v.y) << 16);
      o.y = (unsigned)f2b(v.z) | ((unsigned)f2b(v.w) << 16);
      *(uint2*)(dst + (size_t)idx * 4) = o;
    }
    return;
  }
  b -= NB_FT;
  if (b < NB_WT) {                                 // ---- weight transpose, LDS tile ----
    int mat = b >> 3, sub = b & 7;                 // mat in 0..12 only
    int K = (mat == 12) ? INS : INC;
    if (mat == 12 && sub >= 4) return;
    int k0 = (sub >> 2) * 64, n0 = (sub & 3) * 64;
    const float* src; u16* dst;
    if (mat < 9)        { src = Wcc + (size_t)mat * INC * HD;        dst = wsu + WTCC + (size_t)mat * 32768; }
    else if (mat < 12)  { src = Wcs + (size_t)(mat - 9) * INC * HD;  dst = wsu + WTCS + (size_t)(mat - 9) * 32768; }
    else                { src = Win;                                 dst = wsu + WTIN; }
    #pragma unroll
    for (int it = 0; it < 4; it++) {
      int idx = t + it * 256;
      int r = idx >> 4, c4 = idx & 15;
      float4 v = *(const float4*)&src[(size_t)(k0 + r) * HD + n0 + c4 * 4];
      Ls[r * 65 + c4 * 4 + 0] = v.x; Ls[r * 65 + c4 * 4 + 1] = v.y;
      Ls[r * 65 + c4 * 4 + 2] = v.z; Ls[r * 65 + c4 * 4 + 3] = v.w;
    }
    __syncthreads();
    int n = t >> 2, k8 = (t & 3) * 16;
    unsigned o[8];
    #pragma unroll
    for (int j = 0; j < 8; j++) {
      u16 lo = f2b(Ls[(k8 + 2 * j) * 65 + n]);
      u16 hi = f2b(Ls[(k8 + 2 * j + 1) * 65 + n]);
      o[j] = (unsigned)lo | ((unsigned)hi << 16);
    }
    uint4* dp = (uint4*)&dst[(size_t)(n0 + n) * K + k0 + k8];
    dp[0] = make_uint4(o[0], o[1], o[2], o[3]);
    dp[1] = make_uint4(o[4], o[5], o[6], o[7]);
    return;
  }
  b -= NB_WT;                                      // ---- attn fold: 4 tiles ----
  int tile = b;
  int K = (tile == 3) ? INS : INC;
  for (int idx = t; idx < 64 * K; idx += 256) {
    int col = idx / K, k = idx - col * K;
    int m = col >> 3, h = col & 7;
    const float* W = nullptr; const float* av = nullptr;
    if (tile < 3) {
      if (m < 3)      { int r = 3*tile + m; W = Wcc + (size_t)r*INC*HD;   av = accv + (size_t)r*512 + h*32; }
      else if (m < 6) { int r = 3*(m-3) + tile; W = Wnode + (size_t)tile*INC*HD; av = accv + (size_t)r*512 + 256 + h*32; }
      else if (m == 6){ W = Wcs + (size_t)tile*INC*HD; av = acsv + (size_t)tile*512 + h*32; }
    } else if (m < 3) { W = Win; av = acsv + (size_t)m*512 + 256 + h*32; }
    float s = 0.f;
    if (W) {
      const float* wp = W + (size_t)k * HD + h * 32;
      #pragma unroll 8
      for (int d = 0; d < 32; d++) s += wp[d] * av[d];
    }
    wsu[WAT + (size_t)tile * 8192 + (size_t)col * K + k] = f2b(s);
  }
  if (t < 64) {
    int col = t, m = col >> 3, h = col & 7;
    const float* bb = nullptr; const float* av = nullptr;
    if (tile < 3) {
      if (m < 3)      { int r = 3*tile + m; bb = bcc + (size_t)r*HD;  av = accv + (size_t)r*512 + h*32; }
      else if (m < 6) { int r = 3*(m-3) + tile; bb = bnode + (size_t)tile*HD; av = accv + (size_t)r*512 + 256 + h*32; }
      else if (m == 6){ bb = bcs + (size_t)tile*HD; av = acsv + (size_t)tile*512 + h*32; }
    } else if (m < 3) { bb = bin; av = acsv + (size_t)m*512 + 256 + h*32; }
    float s = 0.f;
    if (bb) for (int d = 0; d < 32; d++) s += bb[h*32 + d] * av[d];
    wsf[BAF + tile * 64 + col] = s;
  }
}

// ================= K2: 13 full GEMMs + 4 score GEMMs =================
__global__ __launch_bounds__(256, 2) void k_gemm(
    u16* wsu, float* wsf, const float* bcc, const float* bcs, const float* bin) {
  __shared__ __align__(16) char smem[69632];
  u16* As = (u16*)smem;
  u16* Bs = (u16*)(smem + 34816);
  int g = blockIdx.x, t = threadIdx.x;
  const u16 *A, *Bt; const float* bias = nullptr; u16* C = nullptr;
  int M, K, r0, n0 = 0, ty = 0;
  bool isScore = false;
  if (g < 1896) {
    int z = g / 158, rem = g - z * 158;
    int by = rem / 79, bx = rem - by * 79;
    r0 = bx * 128; n0 = by * 128; M = NC; K = 128;
    if (z < 9) { A = wsu + FBC + (size_t)(z/3)*1280000; Bt = wsu + WTCC + (size_t)z*32768; bias = bcc + (size_t)z*HD; C = wsu + WHB_CC + (size_t)z*NC*HD; }
    else { int q = z - 9; A = wsu + FBC + (size_t)q*1280000; Bt = wsu + WTCS + (size_t)q*32768; bias = bcs + (size_t)q*HD; C = wsu + WHB_CS + (size_t)q*NC*HD; }
  } else if (g < 1912) {
    int loc = g - 1896; int by = loc / 8, bx = loc - by * 8;
    r0 = bx * 128; n0 = by * 128; M = NS; K = 64;
    A = wsu + FBS; Bt = wsu + WTIN; bias = bin; C = wsu + WHB_IN;
  } else if (g < 2149) {
    isScore = true; ty = (g - 1912) / 79; int bx = (g - 1912) % 79;
    r0 = bx * 128; M = NC; K = 128;
    A = wsu + FBC + (size_t)ty * 1280000; Bt = wsu + WAT + (size_t)ty * 8192;
  } else {
    isScore = true; ty = 3; int bx = g - 2149;
    r0 = bx * 128; M = NS; K = 64;
    A = wsu + FBS; Bt = wsu + WAT + (size_t)3 * 8192;
  }
  int SA = K + 8;
  int NB = isScore ? 64 : 128;
  {
    int ksh = (K == 128) ? 4 : 3;
    int kmask = (1 << ksh) - 1;
    int sc8 = SA >> 3;
    const uint4* ga = (const uint4*)(A + (size_t)r0 * K);
    const uint4* gb = (const uint4*)(Bt + (size_t)n0 * K);
    uint4* la = (uint4*)As; uint4* lb = (uint4*)Bs;
    int tota = (128 * K) >> 3, totb = (NB * K) >> 3;
    for (int i = t; i < tota; i += 256) la[(i >> ksh) * sc8 + (i & kmask)] = ga[i];
    for (int i = t; i < totb; i += 256) lb[(i >> ksh) * sc8 + (i & kmask)] = gb[i];
  }
  __syncthreads();
  int lane = t & 63, w = t >> 6, l16 = lane & 15, quad = lane >> 4;
  int arow0 = w * 32 + l16;
  if (!isScore) {
    f32x4 acc[2][8];
    #pragma unroll
    for (int i = 0; i < 2; i++)
      #pragma unroll
      for (int j = 0; j < 8; j++) acc[i][j] = (f32x4){0.f, 0.f, 0.f, 0.f};
    for (int ks = 0; ks < K; ks += 32) {
      int ko = ks + quad * 8;
      short8 a0 = *(const short8*)&As[(size_t)arow0 * SA + ko];
      short8 a1 = *(const short8*)&As[(size_t)(arow0 + 16) * SA + ko];
      #pragma unroll
      for (int j = 0; j < 8; j++) {
        short8 bfr = *(const short8*)&Bs[(size_t)(j * 16 + l16) * SA + ko];
        acc[0][j] = __builtin_amdgcn_mfma_f32_16x16x32_bf16(a0, bfr, acc[0][j], 0, 0, 0);
        acc[1][j] = __builtin_amdgcn_mfma_f32_16x16x32_bf16(a1, bfr, acc[1][j], 0, 0, 0);
      }
    }
    __syncthreads();
    float* Cl = (float*)smem;            // 128 x 132 (2-way = free on writes)
    #pragma unroll
    for (int i = 0; i < 2; i++) {
      int rl0 = w * 32 + i * 16 + quad * 4;
      #pragma unroll
      for (int j = 0; j < 8; j++) {
        int cl = j * 16 + l16;
        float bv = bias[n0 + cl];
        #pragma unroll
        for (int rg = 0; rg < 4; rg++)
          Cl[(rl0 + rg) * 132 + cl] = acc[i][j][rg] + bv;
      }
    }
    __syncthreads();
    for (int task = t; task < 2048; task += 256) {
      int row = task >> 4, seg = task & 15;
      int gr = r0 + row;
      if (gr >= M) continue;
      const float* cp = Cl + row * 132 + seg * 8;
      float4 v0 = *(const float4*)cp;
      float4 v1 = *(const float4*)(cp + 4);
      uint4 o;
      o.x = (unsigned)f2b(v0.x) | ((unsigned)f2b(v0.y) << 16);
      o.y = (unsigned)f2b(v0.z) | ((unsigned)f2b(v0.w) << 16);
      o.z = (unsigned)f2b(v1.x) | ((unsigned)f2b(v1.y) << 16);
      o.w = (unsigned)f2b(v1.z) | ((unsigned)f2b(v1.w) << 16);
      *(uint4*)&C[(size_t)gr * HD + n0 + seg * 8] = o;
    }
  } else {
    f32x4 acc[2][4];
    #pragma unroll
    for (int i = 0; i < 2; i++)
      #pragma unroll
      for (int j = 0; j < 4; j++) acc[i][j] = (f32x4){0.f, 0.f, 0.f, 0.f};
    for (int ks = 0; ks < K; ks += 32) {
      int ko = ks + quad * 8;
      short8 a0 = *(const short8*)&As[(size_t)arow0 * SA + ko];
      short8 a1 = *(const short8*)&As[(size_t)(arow0 + 16) * SA + ko];
      #pragma unroll
      for (int j = 0; j < 4; j++) {
        short8 bfr = *(const short8*)&Bs[(size_t)(j * 16 + l16) * SA + ko];
        acc[0][j] = __builtin_amdgcn_mfma_f32_16x16x32_bf16(a0, bfr, acc[0][j], 0, 0, 0);
        acc[1][j] = __builtin_amdgcn_mfma_f32_16x16x32_bf16(a1, bfr, acc[1][j], 0, 0, 0);
      }
    }
    // scores: col = j*16+l16 in [0,64); m=col>>3 selects target array, h=col&7
    float* sp[4]; float bav[4];
    #pragma unroll
    for (int j = 0; j < 4; j++) {
      int col = j * 16 + l16;
      int m = col >> 3, h = col & 7;
      float* p = nullptr;
      if (ty < 3) {
        if (m < 3)       p = wsf + ASCC + (size_t)(3*ty + m) * NC * H_;
        else if (m < 6)  p = wsf + ADCC + (size_t)(3*(m-3) + ty) * NC * H_;
        else if (m == 6) p = wsf + ASCS + (size_t)ty * NC * H_;
      } else if (m < 3)  p = wsf + ADCS + (size_t)m * NS * H_;
      sp[j] = p ? (p + h) : nullptr;
      bav[j] = wsf[BAF + ty * 64 + col];
    }
    #pragma unroll
    for (int i = 0; i < 2; i++) {
      int rl0 = w * 32 + i * 16 + quad * 4;
      #pragma unroll
      for (int j = 0; j < 4; j++) {
        if (!sp[j]) continue;
        #pragma unroll
        for (int rg = 0; rg < 4; rg++) {
          int gr = r0 + rl0 + rg;
          if (gr < M) sp[j][(size_t)gr * 8] = acc[i][j][rg] + bav[j];
        }
      }
    }
  }
}

// ================= K3: aggregation, 1 wave/dst node, 4-edge pipeline =================
__global__ __launch_bounds__(256) void k_agg(const u16* wsu, const float* wsf,
                                             const int* cnts, const u16* slt,
                                             float* out) {
  int t = threadIdx.x, lane = t & 63, w = t >> 6;
  int node = blockIdx.x * 4 + w;
  int sub = lane & 31, half = lane >> 5, h = sub >> 2;
  float acc[8] = {0.f, 0.f, 0.f, 0.f, 0.f, 0.f, 0.f, 0.f};
  bool isC = node < 3 * NC;
  int dtype = 0, n;
  if (isC) { dtype = node / NC; n = node - dtype * NC; } else { n = node - 3 * NC; }
  for (int j = 0; j < 3; j++) {
    int cidx; const float* ASp; float adn; const u16* whb;
    if (isC) {
      int r = j * 3 + dtype;
      cidx = r * NC + n;
      ASp  = wsf + ASCC + (size_t)r * NC * H_;
      adn  = wsf[ADCC + (size_t)r * NC * H_ + (size_t)n * H_ + h];
      whb  = wsu + WHB_CC + (size_t)r * NC * HD;
    } else {
      int r = j;
      cidx = 90000 + r * NS + n;
      ASp  = wsf + ASCS + (size_t)r * NC * H_;
      adn  = wsf[ADCS + (size_t)r * NS * H_ + (size_t)n * H_ + h];
      whb  = wsu + WHB_CS + (size_t)r * NC * HD;
    }
    int cnt = cnts[cidx];
    cnt = min(cnt, CAP);
    if (cnt <= 0) continue;
    int vsrc = ((int)slt[(size_t)cidx * CAP + min(lane, cnt - 1)]) << 5;  // src*32 B
    const char* sb_ = (const char*)ASp + h * 4;
    const char* wb_ = (const char*)whb + sub * 16;
    float a8[8] = {0.f, 0.f, 0.f, 0.f, 0.f, 0.f, 0.f, 0.f};
    float sH = 0.f;
    for (int e = 0; e < cnt; e += 4) {
      int i0 = min(e + half, cnt - 1);
      int i1 = min(e + 2 + half, cnt - 1);
      int so0 = __shfl(vsrc, i0);
      int so1 = __shfl(vsrc, i1);
      float sc0 = *(const float*)(sb_ + so0) + adn;
      float sc1 = *(const float*)(sb_ + so1) + adn;
      uint4 m0 = *(const uint4*)(wb_ + ((size_t)so0 << 4));
      uint4 m1 = *(const uint4*)(wb_ + ((size_t)so1 << 4));
      sc0 = fmaxf(sc0, ALPHA * sc0);
      sc1 = fmaxf(sc1, ALPHA * sc1);
      float w0 = (e + half < cnt) ? __expf(sc0) : 0.f;
      float w1 = (e + 2 + half < cnt) ? __expf(sc1) : 0.f;
      a8[0] += w0 * bl(m0.x); a8[1] += w0 * bh(m0.x);
      a8[2] += w0 * bl(m0.y); a8[3] += w0 * bh(m0.y);
      a8[4] += w0 * bl(m0.z); a8[5] += w0 * bh(m0.z);
      a8[6] += w0 * bl(m0.w); a8[7] += w0 * bh(m0.w);
      a8[0] += w1 * bl(m1.x); a8[1] += w1 * bh(m1.x);
      a8[2] += w1 * bl(m1.y); a8[3] += w1 * bh(m1.y);
      a8[4] += w1 * bl(m1.z); a8[5] += w1 * bh(m1.z);
      a8[6] += w1 * bl(m1.w); a8[7] += w1 * bh(m1.w);
      sH += w0 + w1;
    }
    sH += __shfl_xor(sH, 32);
    float inv = 1.f / sH;
    #pragma unroll
    for (int q = 0; q < 8; q++) acc[q] += a8[q] * inv;
  }
  #pragma unroll
  for (int q = 0; q < 8; q++) acc[q] += __shfl_xor(acc[q], 32);
  if (!isC) {
    uint4 m = *(const uint4*)((const char*)(wsu + WHB_IN) + (size_t)n * 512 + sub * 16);
    acc[0] += bl(m.x); acc[1] += bh(m.x); acc[2] += bl(m.y); acc[3] += bh(m.y);
    acc[4] += bl(m.z); acc[5] += bh(m.z); acc[6] += bl(m.w); acc[7] += bh(m.w);
  }
  float4 v;
  if (half == 0) v = make_float4(acc[0], acc[1], acc[2], acc[3]);
  else           v = make_float4(acc[4], acc[5], acc[6], acc[7]);
  v.x = fmaxf(v.x, 0.f); v.y = fmaxf(v.y, 0.f);
  v.z = fmaxf(v.z, 0.f); v.w = fmaxf(v.w, 0.f);
  *(float4*)(out + (size_t)node * HD + sub * 8 + half * 4) = v;
}

extern "C" void kernel_launch(void* const* d_in, const int* in_sizes, int n_in,
                              void* d_out, int out_size, void* d_ws, size_t ws_size,
                              hipStream_t stream) {
  (void)in_sizes; (void)n_in; (void)out_size; (void)ws_size;
  const float* f1    = (const float*)d_in[0];
  const float* f2    = (const float*)d_in[1];
  const float* f3    = (const float*)d_in[2];
  const float* fs    = (const float*)d_in[3];
  const float* Wnode = (const float*)d_in[4];
  const float* bnode = (const float*)d_in[5];
  const float* Wcc   = (const float*)d_in[6];
  const float* bcc   = (const float*)d_in[7];
  const float* Wcs   = (const float*)d_in[8];
  const float* bcs   = (const float*)d_in[9];
  const float* Win   = (const float*)d_in[10];
  const float* bin   = (const float*)d_in[11];
  const float* accv  = (const float*)d_in[12];
  const float* acsv  = (const float*)d_in[13];
  const int* eccs    = (const int*)d_in[14];
  const int* eccd    = (const int*)d_in[15];
  const int* ecss    = (const int*)d_in[16];
  const int* ecsd    = (const int*)d_in[17];
  float* wsf = (float*)d_ws;
  u16*   wsu = (u16*)d_ws;
  int*   cnts = (int*)((char*)d_ws + IBYTE);
  u16*   slt  = (u16*)((char*)d_ws + SBYTE);
  float* out = (float*)d_out;

  hipMemsetAsync((char*)d_ws + IBYTE, 0, 93072 * 4, stream);
  k_prep<<<dim3(NB_SC + NB_FT + NB_WT + NB_FO), 256, 0, stream>>>(
      f1, f2, f3, fs, Wcc, Wcs, Win, Wnode, bcc, bnode, bcs, bin, accv, acsv,
      eccs, eccd, ecss, ecsd, wsu, wsf, cnts, slt);
  k_gemm<<<dim3(NB_GE), 256, 0, stream>>>(wsu, wsf, bcc, bcs, bin);
  k_agg<<<dim3((3 * NC + NS) / 4), 256, 0, stream>>>(wsu, wsf, cnts, slt, out);
}

// Round 10
// 256.994 us; speedup vs baseline: 1.3283x; 1.3283x over previous
//
#include <hip/hip_runtime.h>

// HeteroGAT on MI355X. R10:
//   K1 k_prep: zero counters + feat cvt + W transpose + fold (32 blocks, was 4 -> tail fix)
//   K2 k_fuse: 2157 bf16-MFMA GEMM blocks interleaved 4:1 with 542 scatter blocks
//              (scatter = concurrency-insensitive contention floor -> hide gemm under it)
//   K3 k_agg: 1 wave/dst node, 4-edge software pipeline

#define H_ 8
#define D_ 32
#define HD 256
#define NC 10000
#define NS 1024
#define INC 128
#define INS 64
#define ECC 120000
#define ECS 10000
#define ALPHA 0.2f
#define CAP 64

typedef unsigned short u16;
typedef __attribute__((ext_vector_type(8))) short short8;
typedef __attribute__((ext_vector_type(4))) float f32x4;

// ---- ws layout ----
// u16 region (u16 units)
static constexpr size_t WHB_CC = 0;              // 9*NC*HD
static constexpr size_t WHB_CS = 23040000;       // 3*NC*HD
static constexpr size_t WHB_IN = 30720000;       // NS*HD -> end 30982144 u16
// f32 scores (float units)
static constexpr size_t FB0  = 15491072;
static constexpr size_t ASCC = FB0;              // 9*NC*8
static constexpr size_t ADCC = FB0 + 720000;     // 9*NC*8
static constexpr size_t ASCS = FB0 + 1440000;    // 3*NC*8
static constexpr size_t ADCS = FB0 + 1680000;    // 3*NS*8 -> FB0+1704576
static constexpr size_t BAF  = FB0 + 1704576;    // 4*64 folded bias dots
// bf16 feats + transposed weights (u16 units)
static constexpr size_t FBC  = 34437760;         // 3*NC*128
static constexpr size_t FBS  = 38277760;         // NS*64
static constexpr size_t WTCC = 38343296;         // 9*32768
static constexpr size_t WTCS = 38638208;         // 3*32768
static constexpr size_t WTIN = 38736512;         // 256*64
static constexpr size_t WAT  = 38752896;         // 4*8192 folded attn mats [col][k]
// int counters (byte offset): 93072 ints = 9*NC (cc) then 3*NS (cs)
static constexpr size_t IBYTE = 77768704;
// u16 slots (byte offset): slot for counter c is slt[c*CAP + p]
static constexpr size_t SBYTE = 78140992;

static constexpr int TOTE  = 9 * ECC + 3 * ECS;  // 1,110,000
static constexpr int NB_Z0 = 91;                 // zero: 93072 ints / (int4*256)
static constexpr int NB_FT = 3814;               // feat cvt
static constexpr int NB_WT = 104;                // weight transpose: 13 mats x 8
static constexpr int NB_FO = 32;                 // attn fold: 4 tiles x 8 col-groups
static constexpr int NB_K2 = 2710;               // 542 scatter (g%5==4) + 2168 gemm slots (2157 used)

__device__ __forceinline__ u16 f2b(float f) {
  unsigned u = __float_as_uint(f);
  return (u16)((u + 0x7FFFu + ((u >> 16) & 1u)) >> 16);
}
__device__ __forceinline__ float bl(unsigned u) { return __uint_as_float(u << 16); }
__device__ __forceinline__ float bh(unsigned u) { return __uint_as_float(u & 0xffff0000u); }

// ================= K1: zero + cvt_feat + cvt_w + fold(32) =================
__global__ __launch_bounds__(256) void k_prep(
    const float* f1, const float* f2, const float* f3, const float* fs,
    const float* Wcc, const float* Wcs, const float* Win, const float* Wnode,
    const float* bcc, const float* bnode, const float* bcs, const float* bin,
    const float* accv, const float* acsv,
    u16* wsu, float* wsf, int* cnts) {
  __shared__ float Ls[64 * 65];
  int b = blockIdx.x, t = threadIdx.x;
  if (b < NB_Z0) {                                 // ---- zero counters ----
    int i = b * 256 + t;
    if (i < 23268) ((int4*)cnts)[i] = make_int4(0, 0, 0, 0);
    return;
  }
  b -= NB_Z0;
  if (b < NB_FT) {                                 // ---- f32 -> bf16 feats ----
    const float* src; u16* dst; int idx, n4;
    if (b < 3750) {
      int ty = b / 1250;
      src = (ty == 0) ? f1 : (ty == 1) ? f2 : f3;
      dst = wsu + FBC + (size_t)ty * 1280000;
      idx = (b - ty * 1250) * 256 + t; n4 = 320000;
    } else {
      src = fs; dst = wsu + FBS; idx = (b - 3750) * 256 + t; n4 = 16384;
    }
    if (idx < n4) {
      float4 v = ((const float4*)src)[idx];
      uint2 o;
      o.x = (unsigned)f2b(v.x) | ((unsigned)f2b(v.y) << 16);
      o.y = (unsigned)f2b(v.z) | ((unsigned)f2b(v.w) << 16);
      *(uint2*)(dst + (size_t)idx * 4) = o;
    }
    return;
  }
  b -= NB_FT;
  if (b < NB_WT) {                                 // ---- weight transpose, LDS tile ----
    int mat = b >> 3, sub = b & 7;                 // mat 0..12
    int K = (mat == 12) ? INS : INC;
    if (mat == 12 && sub >= 4) return;
    int k0 = (sub >> 2) * 64, n0 = (sub & 3) * 64;
    const float* src; u16* dst;
    if (mat < 9)        { src = Wcc + (size_t)mat * INC * HD;        dst = wsu + WTCC + (size_t)mat * 32768; }
    else if (mat < 12)  { src = Wcs + (size_t)(mat - 9) * INC * HD;  dst = wsu + WTCS + (size_t)(mat - 9) * 32768; }
    else                { src = Win;                                 dst = wsu + WTIN; }
    #pragma unroll
    for (int it = 0; it < 4; it++) {
      int idx = t + it * 256;
      int r = idx >> 4, c4 = idx & 15;
      float4 v = *(const float4*)&src[(size_t)(k0 + r) * HD + n0 + c4 * 4];
      Ls[r * 65 + c4 * 4 + 0] = v.x; Ls[r * 65 + c4 * 4 + 1] = v.y;
      Ls[r * 65 + c4 * 4 + 2] = v.z; Ls[r * 65 + c4 * 4 + 3] = v.w;
    }
    __syncthreads();
    int n = t >> 2, k8 = (t & 3) * 16;
    unsigned o[8];
    #pragma unroll
    for (int j = 0; j < 8; j++) {
      u16 lo = f2b(Ls[(k8 + 2 * j) * 65 + n]);
      u16 hi = f2b(Ls[(k8 + 2 * j + 1) * 65 + n]);
      o[j] = (unsigned)lo | ((unsigned)hi << 16);
    }
    uint4* dp = (uint4*)&dst[(size_t)(n0 + n) * K + k0 + k8];
    dp[0] = make_uint4(o[0], o[1], o[2], o[3]);
    dp[1] = make_uint4(o[4], o[5], o[6], o[7]);
    return;
  }
  b -= NB_WT;                                      // ---- attn fold: 4 tiles x 8 groups ----
  int tile = b >> 3, sub = b & 7;
  int K = (tile == 3) ? INS : INC;
  int c0 = sub * 8;
  for (int idx = t; idx < 8 * K; idx += 256) {
    int col = c0 + idx / K, k = idx % K;
    int m = col >> 3, h = col & 7;
    const float* W = nullptr; const float* av = nullptr;
    if (tile < 3) {
      if (m < 3)      { int r = 3*tile + m; W = Wcc + (size_t)r*INC*HD;   av = accv + (size_t)r*512 + h*32; }
      else if (m < 6) { int r = 3*(m-3) + tile; W = Wnode + (size_t)tile*INC*HD; av = accv + (size_t)r*512 + 256 + h*32; }
      else if (m == 6){ W = Wcs + (size_t)tile*INC*HD; av = acsv + (size_t)tile*512 + h*32; }
    } else if (m < 3) { W = Win; av = acsv + (size_t)m*512 + 256 + h*32; }
    float s = 0.f;
    if (W) {
      const float* wp = W + (size_t)k * HD + h * 32;
      #pragma unroll 8
      for (int d = 0; d < 32; d++) s += wp[d] * av[d];
    }
    wsu[WAT + (size_t)tile * 8192 + (size_t)col * K + k] = f2b(s);
  }
  if (sub == 0 && t < 64) {
    int col = t, m = col >> 3, h = col & 7;
    const float* bb = nullptr; const float* av = nullptr;
    if (tile < 3) {
      if (m < 3)      { int r = 3*tile + m; bb = bcc + (size_t)r*HD;  av = accv + (size_t)r*512 + h*32; }
      else if (m < 6) { int r = 3*(m-3) + tile; bb = bnode + (size_t)tile*HD; av = accv + (size_t)r*512 + 256 + h*32; }
      else if (m == 6){ bb = bcs + (size_t)tile*HD; av = acsv + (size_t)tile*512 + h*32; }
    } else if (m < 3) { bb = bin; av = acsv + (size_t)m*512 + 256 + h*32; }
    float s = 0.f;
    if (bb) for (int d = 0; d < 32; d++) s += bb[h*32 + d] * av[d];
    wsf[BAF + tile * 64 + col] = s;
  }
}

// ================= K2: interleaved scatter (1 of 5) + GEMMs =================
__global__ __launch_bounds__(256, 2) void k_fuse(
    u16* wsu, float* wsf, const float* bcc, const float* bcs, const float* bin,
    const int* eccs, const int* eccd, const int* ecss, const int* ecsd,
    int* cnts, u16* slt) {
  __shared__ __align__(16) char smem[69632];
  int gb = blockIdx.x, t = threadIdx.x;
  if ((gb % 5) == 4) {                             // ---- edge scatter, 8/thread ----
    int k = gb / 5;                                // 0..541
    int i0 = (k * 256 + t) * 8;
    if (i0 >= TOTE) return;
    int dd[8], ss[8], p[8];
    int cbase;
    if (i0 < 9 * ECC) {
      int r = i0 / ECC;
      int4 d0 = *(const int4*)&eccd[i0]; int4 d1 = *(const int4*)&eccd[i0 + 4];
      int4 s0 = *(const int4*)&eccs[i0]; int4 s1 = *(const int4*)&eccs[i0 + 4];
      dd[0]=d0.x; dd[1]=d0.y; dd[2]=d0.z; dd[3]=d0.w;
      dd[4]=d1.x; dd[5]=d1.y; dd[6]=d1.z; dd[7]=d1.w;
      ss[0]=s0.x; ss[1]=s0.y; ss[2]=s0.z; ss[3]=s0.w;
      ss[4]=s1.x; ss[5]=s1.y; ss[6]=s1.z; ss[7]=s1.w;
      cbase = r * NC;
    } else {
      int u0 = i0 - 9 * ECC;
      int r = u0 / ECS;
      int4 d0 = *(const int4*)&ecsd[u0]; int4 d1 = *(const int4*)&ecsd[u0 + 4];
      int4 s0 = *(const int4*)&ecss[u0]; int4 s1 = *(const int4*)&ecss[u0 + 4];
      dd[0]=d0.x; dd[1]=d0.y; dd[2]=d0.z; dd[3]=d0.w;
      dd[4]=d1.x; dd[5]=d1.y; dd[6]=d1.z; dd[7]=d1.w;
      ss[0]=s0.x; ss[1]=s0.y; ss[2]=s0.z; ss[3]=s0.w;
      ss[4]=s1.x; ss[5]=s1.y; ss[6]=s1.z; ss[7]=s1.w;
      cbase = 90000 + r * NS;
    }
    #pragma unroll
    for (int q = 0; q < 8; q++) p[q] = atomicAdd(&cnts[cbase + dd[q]], 1);
    #pragma unroll
    for (int q = 0; q < 8; q++)
      if (p[q] < CAP) slt[((size_t)(cbase + dd[q])) * CAP + p[q]] = (u16)ss[q];
    return;
  }
  int g = 4 * (gb / 5) + (gb % 5);                 // gemm id 0..2167
  if (g >= 2157) return;
  u16* As = (u16*)smem;
  u16* Bs = (u16*)(smem + 34816);
  const u16 *A, *Bt; const float* bias = nullptr; u16* C = nullptr;
  int M, K, r0, n0 = 0, ty = 0;
  bool isScore = false;
  if (g < 1896) {
    int z = g / 158, rem = g - z * 158;
    int by = rem / 79, bx = rem - by * 79;
    r0 = bx * 128; n0 = by * 128; M = NC; K = 128;
    if (z < 9) { A = wsu + FBC + (size_t)(z/3)*1280000; Bt = wsu + WTCC + (size_t)z*32768; bias = bcc + (size_t)z*HD; C = wsu + WHB_CC + (size_t)z*NC*HD; }
    else { int q = z - 9; A = wsu + FBC + (size_t)q*1280000; Bt = wsu + WTCS + (size_t)q*32768; bias = bcs + (size_t)q*HD; C = wsu + WHB_CS + (size_t)q*NC*HD; }
  } else if (g < 1912) {
    int loc = g - 1896; int by = loc / 8, bx = loc - by * 8;
    r0 = bx * 128; n0 = by * 128; M = NS; K = 64;
    A = wsu + FBS; Bt = wsu + WTIN; bias = bin; C = wsu + WHB_IN;
  } else if (g < 2149) {
    isScore = true; ty = (g - 1912) / 79; int bx = (g - 1912) % 79;
    r0 = bx * 128; M = NC; K = 128;
    A = wsu + FBC + (size_t)ty * 1280000; Bt = wsu + WAT + (size_t)ty * 8192;
  } else {
    isScore = true; ty = 3; int bx = g - 2149;
    r0 = bx * 128; M = NS; K = 64;
    A = wsu + FBS; Bt = wsu + WAT + (size_t)3 * 8192;
  }
  int SA = K + 8;
  int NB = isScore ? 64 : 128;
  {
    int ksh = (K == 128) ? 4 : 3;
    int kmask = (1 << ksh) - 1;
    int sc8 = SA >> 3;
    const uint4* ga = (const uint4*)(A + (size_t)r0 * K);
    const uint4* gb2 = (const uint4*)(Bt + (size_t)n0 * K);
    uint4* la = (uint4*)As; uint4* lb = (uint4*)Bs;
    int tota = (128 * K) >> 3, totb = (NB * K) >> 3;
    for (int i = t; i < tota; i += 256) la[(i >> ksh) * sc8 + (i & kmask)] = ga[i];
    for (int i = t; i < totb; i += 256) lb[(i >> ksh) * sc8 + (i & kmask)] = gb2[i];
  }
  __syncthreads();
  int lane = t & 63, w = t >> 6, l16 = lane & 15, quad = lane >> 4;
  int arow0 = w * 32 + l16;
  if (!isScore) {
    f32x4 acc[2][8];
    #pragma unroll
    for (int i = 0; i < 2; i++)
      #pragma unroll
      for (int j = 0; j < 8; j++) acc[i][j] = (f32x4){0.f, 0.f, 0.f, 0.f};
    for (int ks = 0; ks < K; ks += 32) {
      int ko = ks + quad * 8;
      short8 a0 = *(const short8*)&As[(size_t)arow0 * SA + ko];
      short8 a1 = *(const short8*)&As[(size_t)(arow0 + 16) * SA + ko];
      #pragma unroll
      for (int j = 0; j < 8; j++) {
        short8 bfr = *(const short8*)&Bs[(size_t)(j * 16 + l16) * SA + ko];
        acc[0][j] = __builtin_amdgcn_mfma_f32_16x16x32_bf16(a0, bfr, acc[0][j], 0, 0, 0);
        acc[1][j] = __builtin_amdgcn_mfma_f32_16x16x32_bf16(a1, bfr, acc[1][j], 0, 0, 0);
      }
    }
    __syncthreads();
    float* Cl = (float*)smem;            // 128 x 132 (2-way = free)
    #pragma unroll
    for (int i = 0; i < 2; i++) {
      int rl0 = w * 32 + i * 16 + quad * 4;
      #pragma unroll
      for (int j = 0; j < 8; j++) {
        int cl = j * 16 + l16;
        float bv = bias[n0 + cl];
        #pragma unroll
        for (int rg = 0; rg < 4; rg++)
          Cl[(rl0 + rg) * 132 + cl] = acc[i][j][rg] + bv;
      }
    }
    __syncthreads();
    for (int task = t; task < 2048; task += 256) {
      int row = task >> 4, seg = task & 15;
      int gr = r0 + row;
      if (gr >= M) continue;
      const float* cp = Cl + row * 132 + seg * 8;
      float4 v0 = *(const float4*)cp;
      float4 v1 = *(const float4*)(cp + 4);
      uint4 o;
      o.x = (unsigned)f2b(v0.x) | ((unsigned)f2b(v0.y) << 16);
      o.y = (unsigned)f2b(v0.z) | ((unsigned)f2b(v0.w) << 16);
      o.z = (unsigned)f2b(v1.x) | ((unsigned)f2b(v1.y) << 16);
      o.w = (unsigned)f2b(v1.z) | ((unsigned)f2b(v1.w) << 16);
      *(uint4*)&C[(size_t)gr * HD + n0 + seg * 8] = o;
    }
  } else {
    f32x4 acc[2][4];
    #pragma unroll
    for (int i = 0; i < 2; i++)
      #pragma unroll
      for (int j = 0; j < 4; j++) acc[i][j] = (f32x4){0.f, 0.f, 0.f, 0.f};
    for (int ks = 0; ks < K; ks += 32) {
      int ko = ks + quad * 8;
      short8 a0 = *(const short8*)&As[(size_t)arow0 * SA + ko];
      short8 a1 = *(const short8*)&As[(size_t)(arow0 + 16) * SA + ko];
      #pragma unroll
      for (int j = 0; j < 4; j++) {
        short8 bfr = *(const short8*)&Bs[(size_t)(j * 16 + l16) * SA + ko];
        acc[0][j] = __builtin_amdgcn_mfma_f32_16x16x32_bf16(a0, bfr, acc[0][j], 0, 0, 0);
        acc[1][j] = __builtin_amdgcn_mfma_f32_16x16x32_bf16(a1, bfr, acc[1][j], 0, 0, 0);
      }
    }
    float* sp[4]; float bav[4];
    #pragma unroll
    for (int j = 0; j < 4; j++) {
      int col = j * 16 + l16;
      int m = col >> 3, h = col & 7;
      float* p = nullptr;
      if (ty < 3) {
        if (m < 3)       p = wsf + ASCC + (size_t)(3*ty + m) * NC * H_;
        else if (m < 6)  p = wsf + ADCC + (size_t)(3*(m-3) + ty) * NC * H_;
        else if (m == 6) p = wsf + ASCS + (size_t)ty * NC * H_;
      } else if (m < 3)  p = wsf + ADCS + (size_t)m * NS * H_;
      sp[j] = p ? (p + h) : nullptr;
      bav[j] = wsf[BAF + ty * 64 + col];
    }
    #pragma unroll
    for (int i = 0; i < 2; i++) {
      int rl0 = w * 32 + i * 16 + quad * 4;
      #pragma unroll
      for (int j = 0; j < 4; j++) {
        if (!sp[j]) continue;
        #pragma unroll
        for (int rg = 0; rg < 4; rg++) {
          int gr = r0 + rl0 + rg;
          if (gr < M) sp[j][(size_t)gr * 8] = acc[i][j][rg] + bav[j];
        }
      }
    }
  }
}

// ================= K3: aggregation, 1 wave/dst node, 4-edge pipeline =================
__global__ __launch_bounds__(256) void k_agg(const u16* wsu, const float* wsf,
                                             const int* cnts, const u16* slt,
                                             float* out) {
  int t = threadIdx.x, lane = t & 63, w = t >> 6;
  int node = blockIdx.x * 4 + w;
  int sub = lane & 31, half = lane >> 5, h = sub >> 2;
  float acc[8] = {0.f, 0.f, 0.f, 0.f, 0.f, 0.f, 0.f, 0.f};
  bool isC = node < 3 * NC;
  int dtype = 0, n;
  if (isC) { dtype = node / NC; n = node - dtype * NC; } else { n = node - 3 * NC; }
  for (int j = 0; j < 3; j++) {
    int cidx; const float* ASp; float adn; const u16* whb;
    if (isC) {
      int r = j * 3 + dtype;
      cidx = r * NC + n;
      ASp  = wsf + ASCC + (size_t)r * NC * H_;
      adn  = wsf[ADCC + (size_t)r * NC * H_ + (size_t)n * H_ + h];
      whb  = wsu + WHB_CC + (size_t)r * NC * HD;
    } else {
      int r = j;
      cidx = 90000 + r * NS + n;
      ASp  = wsf + ASCS + (size_t)r * NC * H_;
      adn  = wsf[ADCS + (size_t)r * NS * H_ + (size_t)n * H_ + h];
      whb  = wsu + WHB_CS + (size_t)r * NC * HD;
    }
    int cnt = cnts[cidx];
    cnt = min(cnt, CAP);
    if (cnt <= 0) continue;
    int vsrc = ((int)slt[(size_t)cidx * CAP + min(lane, cnt - 1)]) << 5;  // src*32 B
    const char* sb_ = (const char*)ASp + h * 4;
    const char* wb_ = (const char*)whb + sub * 16;
    float a8[8] = {0.f, 0.f, 0.f, 0.f, 0.f, 0.f, 0.f, 0.f};
    float sH = 0.f;
    for (int e = 0; e < cnt; e += 4) {
      int i0 = min(e + half, cnt - 1);
      int i1 = min(e + 2 + half, cnt - 1);
      int so0 = __shfl(vsrc, i0);
      int so1 = __shfl(vsrc, i1);
      float sc0 = *(const float*)(sb_ + so0) + adn;
      float sc1 = *(const float*)(sb_ + so1) + adn;
      uint4 m0 = *(const uint4*)(wb_ + ((size_t)so0 << 4));
      uint4 m1 = *(const uint4*)(wb_ + ((size_t)so1 << 4));
      sc0 = fmaxf(sc0, ALPHA * sc0);
      sc1 = fmaxf(sc1, ALPHA * sc1);
      float w0 = (e + half < cnt) ? __expf(sc0) : 0.f;
      float w1 = (e + 2 + half < cnt) ? __expf(sc1) : 0.f;
      a8[0] += w0 * bl(m0.x); a8[1] += w0 * bh(m0.x);
      a8[2] += w0 * bl(m0.y); a8[3] += w0 * bh(m0.y);
      a8[4] += w0 * bl(m0.z); a8[5] += w0 * bh(m0.z);
      a8[6] += w0 * bl(m0.w); a8[7] += w0 * bh(m0.w);
      a8[0] += w1 * bl(m1.x); a8[1] += w1 * bh(m1.x);
      a8[2] += w1 * bl(m1.y); a8[3] += w1 * bh(m1.y);
      a8[4] += w1 * bl(m1.z); a8[5] += w1 * bh(m1.z);
      a8[6] += w1 * bl(m1.w); a8[7] += w1 * bh(m1.w);
      sH += w0 + w1;
    }
    sH += __shfl_xor(sH, 32);
    float inv = 1.f / sH;
    #pragma unroll
    for (int q = 0; q < 8; q++) acc[q] += a8[q] * inv;
  }
  #pragma unroll
  for (int q = 0; q < 8; q++) acc[q] += __shfl_xor(acc[q], 32);
  if (!isC) {
    uint4 m = *(const uint4*)((const char*)(wsu + WHB_IN) + (size_t)n * 512 + sub * 16);
    acc[0] += bl(m.x); acc[1] += bh(m.x); acc[2] += bl(m.y); acc[3] += bh(m.y);
    acc[4] += bl(m.z); acc[5] += bh(m.z); acc[6] += bl(m.w); acc[7] += bh(m.w);
  }
  float4 v;
  if (half == 0) v = make_float4(acc[0], acc[1], acc[2], acc[3]);
  else           v = make_float4(acc[4], acc[5], acc[6], acc[7]);
  v.x = fmaxf(v.x, 0.f); v.y = fmaxf(v.y, 0.f);
  v.z = fmaxf(v.z, 0.f); v.w = fmaxf(v.w, 0.f);
  *(float4*)(out + (size_t)node * HD + sub * 8 + half * 4) = v;
}

extern "C" void kernel_launch(void* const* d_in, const int* in_sizes, int n_in,
                              void* d_out, int out_size, void* d_ws, size_t ws_size,
                              hipStream_t stream) {
  (void)in_sizes; (void)n_in; (void)out_size; (void)ws_size;
  const float* f1    = (const float*)d_in[0];
  const float* f2    = (const float*)d_in[1];
  const float* f3    = (const float*)d_in[2];
  const float* fs    = (const float*)d_in[3];
  const float* Wnode = (const float*)d_in[4];
  const float* bnode = (const float*)d_in[5];
  const float* Wcc   = (const float*)d_in[6];
  const float* bcc   = (const float*)d_in[7];
  const float* Wcs   = (const float*)d_in[8];
  const float* bcs   = (const float*)d_in[9];
  const float* Win   = (const float*)d_in[10];
  const float* bin   = (const float*)d_in[11];
  const float* accv  = (const float*)d_in[12];
  const float* acsv  = (const float*)d_in[13];
  const int* eccs    = (const int*)d_in[14];
  const int* eccd    = (const int*)d_in[15];
  const int* ecss    = (const int*)d_in[16];
  const int* ecsd    = (const int*)d_in[17];
  float* wsf = (float*)d_ws;
  u16*   wsu = (u16*)d_ws;
  int*   cnts = (int*)((char*)d_ws + IBYTE);
  u16*   slt  = (u16*)((char*)d_ws + SBYTE);
  float* out = (float*)d_out;

  k_prep<<<dim3(NB_Z0 + NB_FT + NB_WT + NB_FO), 256, 0, stream>>>(
      f1, f2, f3, fs, Wcc, Wcs, Win, Wnode, bcc, bnode, bcs, bin, accv, acsv,
      wsu, wsf, cnts);
  k_fuse<<<dim3(NB_K2), 256, 0, stream>>>(
      wsu, wsf, bcc, bcs, bin, eccs, eccd, ecss, ecsd, cnts, slt);
  k_agg<<<dim3((3 * NC + NS) / 4), 256, 0, stream>>>(wsu, wsf, cnts, slt, out);
}